// Round 13
// baseline (197.650 us; speedup 1.0000x reference)
//
#include <hip/hip_runtime.h>

typedef short bf16x8 __attribute__((ext_vector_type(8)));
typedef float f32x4 __attribute__((ext_vector_type(4)));

#define D 128
#define NROW 98304          // 3 groups * 64 mc * 512 rows
#define X_ELEMS ((size_t)NROW * D)          // bf16 elements in ws
#define NBLK 2048                           // dist blocks (BA+BC only; AC is analytic)
#define INV_COUNT 5.9604644775390625e-08f   // 1 / (64*512*512)

typedef __attribute__((address_space(3))) void  as3_void;
typedef const __attribute__((address_space(1))) void as1_cvoid;

__device__ __forceinline__ void gl2lds16(const void* g, void* l) {
    __builtin_amdgcn_global_load_lds((as1_cvoid*)g, (as3_void*)l, 16, 0, 0);
}
__device__ __forceinline__ void gl2lds4(const void* g, void* l) {
    __builtin_amdgcn_global_load_lds((as1_cvoid*)g, (as3_void*)l, 4, 0, 0);
}

__device__ __forceinline__ unsigned short f2bf(float f) {
    unsigned u = __float_as_uint(f);
    u += 0x7FFFu + ((u >> 16) & 1u);        // round-to-nearest-even
    return (unsigned short)(u >> 16);
}
__device__ __forceinline__ float bf2f(unsigned short h) {
    return __uint_as_float(((unsigned)h) << 16);
}

// 8 rows per block; 32 threads per row: float4 loads, 8B bf16 store,
// width-32 shuffle reduce for sum(x_bf16^2).
__global__ __launch_bounds__(256) void prep_kernel(
    const float* __restrict__ mu, const float* __restrict__ sigma,
    const float* __restrict__ epsA, const float* __restrict__ epsB,
    const float* __restrict__ epsC,
    unsigned short* __restrict__ Xb, float* __restrict__ sumsq)
{
    int t = threadIdx.x;
    int row  = blockIdx.x * 8 + (t >> 5);   // 0..NROW-1
    int ci   = t & 31;                      // float4 index within row
    int n  = row & 511;
    int gm = row >> 9;        // g*64 + m
    int g  = gm >> 6;
    int m  = gm & 63;
    const float* eps = (g == 0) ? epsA : (g == 1) ? epsB : epsC;
    float4 e = ((const float4*)(eps + ((size_t)m * 512 + n) * D))[ci];
    float4 u = ((const float4*)(mu    + ((size_t)(g * 512 + n)) * D))[ci];
    float4 s = ((const float4*)(sigma + ((size_t)(g * 512 + n)) * D))[ci];
    unsigned short b0 = f2bf(fmaf(s.x, e.x, u.x));
    unsigned short b1 = f2bf(fmaf(s.y, e.y, u.y));
    unsigned short b2 = f2bf(fmaf(s.z, e.z, u.z));
    unsigned short b3 = f2bf(fmaf(s.w, e.w, u.w));
    float f0 = bf2f(b0), f1 = bf2f(b1), f2 = bf2f(b2), f3 = bf2f(b3);
    float ss = f0 * f0 + f1 * f1 + f2 * f2 + f3 * f3;
    uint2 packed;
    packed.x = (unsigned)b0 | ((unsigned)b1 << 16);
    packed.y = (unsigned)b2 | ((unsigned)b3 << 16);
    ((uint2*)(Xb + (size_t)row * D))[ci] = packed;
    #pragma unroll
    for (int o = 16; o > 0; o >>= 1) ss += __shfl_down(ss, o, 32);
    if (ci == 0) sumsq[row] = ss;
}

// Column sums for the analytic pos term: Ssum[sidx][c] = sum_n X[slice][n][c].
// sidx 0..63 = A slices (mc 0..63), 64..127 = C slices. 128 blocks.
__global__ __launch_bounds__(256) void colsum_kernel(
    const unsigned short* __restrict__ Xb, float* __restrict__ Ssum)
{
    const int sidx = blockIdx.x;          // 0..127
    const int g01  = sidx >> 6;           // 0=A, 1=C
    const int m    = sidx & 63;
    const int ga   = g01 ? 2 : 0;
    const unsigned short* base = Xb + (((size_t)(ga * 64 + m)) * 512) * D;
    const int t = threadIdx.x;
    const int c = t & 127;                // column
    const int h = t >> 7;                 // row parity
    float acc = 0.f;
    for (int r = h; r < 512; r += 2)
        acc += bf2f(base[(size_t)r * D + c]);
    __shared__ float part[256];
    part[t] = acc;
    __syncthreads();
    if (t < 128) Ssum[sidx * 128 + t] = part[t] + part[t + 128];
}

// One block = one 128x128 tile of BA or BC (AC eliminated analytically).
// K=128 in two stage+compute phases through one 33.8 KB LDS set ->
// 4 blocks/CU (HW cap for the 64-reg accumulator). global_load_lds DMA
// from the XCD-local L2 (slice swizzle). Epilogue is uniformly the
// relu(M-d)^2 path now (no per-block branch divergence).
__global__ __launch_bounds__(256, 4) void dist_kernel(
    const unsigned short* __restrict__ Xb, const float* __restrict__ sumsq,
    float* __restrict__ pslots)
{
    const int bx   = blockIdx.x;          // 0..2047
    const int xcd  = bx & 7;
    const int k    = bx >> 3;             // 0..255
    const int j    = k >> 4;              // 0..15
    const int tile = k & 15;
    const int s    = xcd + 8 * j;         // slice 0..127 = dist01*64 + m
    const int d01  = s >> 6;              // 0: BA, 1: BC
    const int m    = s & 63;
    const int tn   = tile >> 2, tk = tile & 3;

    const int gx = 1;                     // x is always B
    const int gy = d01 ? 2 : 0;           // y: A for BA, C for BC

    const char* Xa = (const char*)(Xb + (((size_t)(gx * 64 + m)) * 512 + tn * 128) * D);
    const char* Xc = (const char*)(Xb + (((size_t)(gy * 64 + m)) * 512 + tk * 128) * D);
    const float* ssx = sumsq + ((size_t)(gx * 64 + m)) * 512 + tn * 128;
    const float* ssy = sumsq + ((size_t)(gy * 64 + m)) * 512 + tk * 128;

    __shared__ unsigned short As[128 * 64];   // 16 KB, half-K A
    __shared__ unsigned short Bs[128 * 64];   // 16 KB, half-K B
    __shared__ float ss_s[256];               // x2 rows | y2 rows

    const int t = threadIdx.x;
    const int wave = t >> 6, lane = t & 63;
    const int wr = (wave >> 1) * 64;      // wave's 64x64 quadrant
    const int wc = (wave & 1) * 64;
    const int l15 = lane & 15, quad = lane >> 4;

    // staging lane map: 8 rows x 8 granules per instr (1 KB).
    const int dr8 = lane >> 3, g8 = lane & 7;
    const int voff = dr8 * 256 + ((g8 ^ dr8) * 16);

    f32x4 acc[4][4] = {};

    // ---- phase 0: stage K-cols [0,64) + ss rows ----
    #pragma unroll
    for (int i = 0; i < 4; i++) {
        const int r0 = wave * 32 + i * 8;
        gl2lds16(Xa + r0 * 256 + voff, &As[r0 * 64]);
        gl2lds16(Xc + r0 * 256 + voff, &Bs[r0 * 64]);
    }
    {
        const float* sp = (wave & 2) ? ssy : ssx;
        gl2lds4(sp + (wave & 1) * 64 + lane, &ss_s[wave * 64]);
    }
    __syncthreads();

    #pragma unroll
    for (int ks = 0; ks < 2; ks++) {
        const int base = ((ks * 4 + quad) ^ (l15 & 7)) * 8;
        bf16x8 a[4], b[4];
        #pragma unroll
        for (int fr = 0; fr < 4; fr++)
            a[fr] = *(bf16x8*)&As[(wr + fr * 16 + l15) * 64 + base];
        #pragma unroll
        for (int fc = 0; fc < 4; fc++)
            b[fc] = *(bf16x8*)&Bs[(wc + fc * 16 + l15) * 64 + base];
        #pragma unroll
        for (int fr = 0; fr < 4; fr++)
            #pragma unroll
            for (int fc = 0; fc < 4; fc++)
                acc[fr][fc] = __builtin_amdgcn_mfma_f32_16x16x32_bf16(
                    a[fr], b[fc], acc[fr][fc], 0, 0, 0);
    }
    __syncthreads();

    // ---- phase 1: stage K-cols [64,128) into the same buffer ----
    #pragma unroll
    for (int i = 0; i < 4; i++) {
        const int r0 = wave * 32 + i * 8;
        gl2lds16(Xa + r0 * 256 + 128 + voff, &As[r0 * 64]);
        gl2lds16(Xc + r0 * 256 + 128 + voff, &Bs[r0 * 64]);
    }
    __syncthreads();

    #pragma unroll
    for (int ks = 0; ks < 2; ks++) {
        const int base = ((ks * 4 + quad) ^ (l15 & 7)) * 8;
        bf16x8 a[4], b[4];
        #pragma unroll
        for (int fr = 0; fr < 4; fr++)
            a[fr] = *(bf16x8*)&As[(wr + fr * 16 + l15) * 64 + base];
        #pragma unroll
        for (int fc = 0; fc < 4; fc++)
            b[fc] = *(bf16x8*)&Bs[(wc + fc * 16 + l15) * 64 + base];
        #pragma unroll
        for (int fr = 0; fr < 4; fr++)
            #pragma unroll
            for (int fc = 0; fc < 4; fc++)
                acc[fr][fc] = __builtin_amdgcn_mfma_f32_16x16x32_bf16(
                    a[fr], b[fc], acc[fr][fc], 0, 0, 0);
    }

    // ---- epilogue: d2 = x2 + y2 - 2*dot; relu(2 - d)^2 only ----
    float lsum = 0.f;
    #pragma unroll
    for (int fc = 0; fc < 4; fc++) {
        float y2 = ss_s[128 + wc + fc * 16 + l15];
        #pragma unroll
        for (int fr = 0; fr < 4; fr++) {
            #pragma unroll
            for (int i = 0; i < 4; i++) {
                float x2 = ss_s[wr + fr * 16 + quad * 4 + i];
                float d2 = fmaxf(fmaf(-2.f, acc[fr][fc][i], x2 + y2), 1e-12f);
                if (d2 < 4.f) {                       // relu(M - d), M=2
                    float td = 2.f - sqrtf(d2);
                    lsum += td * td;
                }
            }
        }
    }

    #pragma unroll
    for (int o = 32; o > 0; o >>= 1) lsum += __shfl_down(lsum, o, 64);
    __syncthreads();                      // ss_s reads done; safe to reuse
    float* red = ss_s;
    if (lane == 0) red[wave] = lsum;
    __syncthreads();
    if (t == 0)
        pslots[bx] = red[0] + red[1] + red[2] + red[3];   // plain store, no atomic
}

// Final reduction: neg from pslots; pos analytically:
// pos = (sum sumsq_A + sum sumsq_C)/(64*512) - 2*sum_mc(S_A . S_C)/(64*512^2)
__global__ __launch_bounds__(256) void reduce_kernel(
    const float* __restrict__ pslots, const float* __restrict__ sumsq,
    const float* __restrict__ Ssum, float* __restrict__ out)
{
    const int t = threadIdx.x;
    float neg = 0.f;
    #pragma unroll
    for (int i = 0; i < 2; i++) {
        float4 v = ((const float4*)pslots)[t + i * 256];
        neg += v.x + v.y + v.z + v.w;
    }
    float ssum = 0.f;
    for (int i = t; i < 8192; i += 256) {          // 32768 floats each, as float4
        float4 v = ((const float4*)sumsq)[i];               // group A rows
        float4 w = ((const float4*)(sumsq + 65536))[i];     // group C rows
        ssum += v.x + v.y + v.z + v.w + w.x + w.y + w.z + w.w;
    }
    float dot = 0.f;
    for (int i = t; i < 2048; i += 256) {          // 64 mc x 32 float4 dims
        int mc = i >> 5, d4 = i & 31;
        float4 a = ((const float4*)(Ssum + mc * 128))[d4];
        float4 c = ((const float4*)(Ssum + (64 + mc) * 128))[d4];
        dot += a.x * c.x + a.y * c.y + a.z * c.z + a.w * c.w;
    }
    #pragma unroll
    for (int o = 32; o > 0; o >>= 1) {
        neg  += __shfl_down(neg,  o, 64);
        ssum += __shfl_down(ssum, o, 64);
        dot  += __shfl_down(dot,  o, 64);
    }
    __shared__ float r0[4], r1[4], r2[4];
    const int wave = t >> 6, lane = t & 63;
    if (lane == 0) { r0[wave] = neg; r1[wave] = ssum; r2[wave] = dot; }
    __syncthreads();
    if (t == 0) {
        float neg_t  = r0[0] + r0[1] + r0[2] + r0[3];
        float ssum_t = r1[0] + r1[1] + r1[2] + r1[3];
        float dot_t  = r2[0] + r2[1] + r2[2] + r2[3];
        float pos = ssum_t * (1.f / 32768.f) - 2.f * dot_t * (1.f / 16777216.f);
        out[0] = pos + neg_t * INV_COUNT;
    }
}

extern "C" void kernel_launch(void* const* d_in, const int* in_sizes, int n_in,
                              void* d_out, int out_size, void* d_ws, size_t ws_size,
                              hipStream_t stream) {
    const float* mu    = (const float*)d_in[0];
    const float* sigma = (const float*)d_in[1];
    const float* epsA  = (const float*)d_in[2];
    const float* epsB  = (const float*)d_in[3];
    const float* epsC  = (const float*)d_in[4];
    float* out = (float*)d_out;

    unsigned short* Xb = (unsigned short*)d_ws;              // 25.17 MB bf16
    float* sumsq  = (float*)((char*)d_ws + X_ELEMS * sizeof(unsigned short)); // 384 KB
    float* pslots = sumsq + NROW;                            // 8 KB partials
    float* Ssum   = pslots + NBLK;                           // 64 KB col sums

    prep_kernel<<<NROW / 8, 256, 0, stream>>>(mu, sigma, epsA, epsB, epsC, Xb, sumsq);

    colsum_kernel<<<128, 256, 0, stream>>>(Xb, Ssum);

    dist_kernel<<<NBLK, 256, 0, stream>>>(Xb, sumsq, pslots);

    reduce_kernel<<<1, 256, 0, stream>>>(pslots, sumsq, Ssum, out);
}

// Round 14
// 140.525 us; speedup vs baseline: 1.4065x; 1.4065x over previous
//
#include <hip/hip_runtime.h>

typedef short bf16x8 __attribute__((ext_vector_type(8)));
typedef float f32x4 __attribute__((ext_vector_type(4)));

#define D 128
#define NROW 98304          // 3 groups * 64 mc * 512 rows
#define X_ELEMS ((size_t)NROW * D)          // bf16 elements in ws
#define NBLK 2048                           // dist blocks (BA+BC only; AC is analytic)
#define INV_COUNT 5.9604644775390625e-08f   // 1 / (64*512*512)

typedef __attribute__((address_space(3))) void  as3_void;
typedef const __attribute__((address_space(1))) void as1_cvoid;

__device__ __forceinline__ void gl2lds16(const void* g, void* l) {
    __builtin_amdgcn_global_load_lds((as1_cvoid*)g, (as3_void*)l, 16, 0, 0);
}
__device__ __forceinline__ void gl2lds4(const void* g, void* l) {
    __builtin_amdgcn_global_load_lds((as1_cvoid*)g, (as3_void*)l, 4, 0, 0);
}

__device__ __forceinline__ unsigned short f2bf(float f) {
    unsigned u = __float_as_uint(f);
    u += 0x7FFFu + ((u >> 16) & 1u);        // round-to-nearest-even
    return (unsigned short)(u >> 16);
}
__device__ __forceinline__ float bf2f(unsigned short h) {
    return __uint_as_float(((unsigned)h) << 16);
}

// 8 rows per block; 32 threads per row: float4 loads, 8B bf16 store,
// width-32 shuffle reduce for sum(x_bf16^2).
__global__ __launch_bounds__(256) void prep_kernel(
    const float* __restrict__ mu, const float* __restrict__ sigma,
    const float* __restrict__ epsA, const float* __restrict__ epsB,
    const float* __restrict__ epsC,
    unsigned short* __restrict__ Xb, float* __restrict__ sumsq)
{
    int t = threadIdx.x;
    int row  = blockIdx.x * 8 + (t >> 5);   // 0..NROW-1
    int ci   = t & 31;                      // float4 index within row
    int n  = row & 511;
    int gm = row >> 9;        // g*64 + m
    int g  = gm >> 6;
    int m  = gm & 63;
    const float* eps = (g == 0) ? epsA : (g == 1) ? epsB : epsC;
    float4 e = ((const float4*)(eps + ((size_t)m * 512 + n) * D))[ci];
    float4 u = ((const float4*)(mu    + ((size_t)(g * 512 + n)) * D))[ci];
    float4 s = ((const float4*)(sigma + ((size_t)(g * 512 + n)) * D))[ci];
    unsigned short b0 = f2bf(fmaf(s.x, e.x, u.x));
    unsigned short b1 = f2bf(fmaf(s.y, e.y, u.y));
    unsigned short b2 = f2bf(fmaf(s.z, e.z, u.z));
    unsigned short b3 = f2bf(fmaf(s.w, e.w, u.w));
    float f0 = bf2f(b0), f1 = bf2f(b1), f2 = bf2f(b2), f3 = bf2f(b3);
    float ss = f0 * f0 + f1 * f1 + f2 * f2 + f3 * f3;
    uint2 packed;
    packed.x = (unsigned)b0 | ((unsigned)b1 << 16);
    packed.y = (unsigned)b2 | ((unsigned)b3 << 16);
    ((uint2*)(Xb + (size_t)row * D))[ci] = packed;
    #pragma unroll
    for (int o = 16; o > 0; o >>= 1) ss += __shfl_down(ss, o, 32);
    if (ci == 0) sumsq[row] = ss;
}

// Column-sum partials for the analytic pos term. 512 blocks = 128 slices x
// 4 row-chunks. Thread (rr=t>>4, gr=t&15): coalesced uint4 loads (8 cols),
// 8 fp32 column partials over rows rr, rr+16, ..; LDS reduce over the 16
// row-threads; write Psum[blk][128]. (R13's colsum was 62 us: 128 blocks +
// scalar 2 B loads = issue-bound. This is 512 blocks + 16 B loads.)
__global__ __launch_bounds__(256) void colsum_kernel(
    const unsigned short* __restrict__ Xb, float* __restrict__ Psum)
{
    const int blk   = blockIdx.x;         // 0..511
    const int sidx  = blk >> 2;           // 0..127 (0-63: A, 64-127: C)
    const int chunk = blk & 3;            // 128-row chunk
    const int g01 = sidx >> 6;
    const int m   = sidx & 63;
    const int ga  = g01 ? 2 : 0;
    const unsigned short* base =
        Xb + (((size_t)(ga * 64 + m)) * 512 + chunk * 128) * D;
    const int t  = threadIdx.x;
    const int gr = t & 15;                // granule: cols gr*8 .. gr*8+7
    const int rr = t >> 4;                // row thread 0..15
    float cs[8] = {};
    for (int r = rr; r < 128; r += 16) {
        uint4 v = *(const uint4*)(base + (size_t)r * D + gr * 8);
        const unsigned short* u = (const unsigned short*)&v;
        #pragma unroll
        for (int j = 0; j < 8; j++) cs[j] += bf2f(u[j]);
    }
    __shared__ float part[16][128];
    #pragma unroll
    for (int j = 0; j < 8; j++) part[rr][gr * 8 + j] = cs[j];
    __syncthreads();
    if (t < 128) {
        float s = 0.f;
        #pragma unroll
        for (int i = 0; i < 16; i++) s += part[i][t];
        Psum[blk * 128 + t] = s;
    }
}

// One block = one 128x128 tile of BA or BC (AC eliminated analytically).
// K=128 in two stage+compute phases through one 33.8 KB LDS set ->
// 4 blocks/CU (HW cap for the 64-reg accumulator). global_load_lds DMA
// from the XCD-local L2 (slice swizzle). Epilogue uniformly relu(M-d)^2.
__global__ __launch_bounds__(256, 4) void dist_kernel(
    const unsigned short* __restrict__ Xb, const float* __restrict__ sumsq,
    float* __restrict__ pslots)
{
    const int bx   = blockIdx.x;          // 0..2047
    const int xcd  = bx & 7;
    const int k    = bx >> 3;             // 0..255
    const int j    = k >> 4;              // 0..15
    const int tile = k & 15;
    const int s    = xcd + 8 * j;         // slice 0..127 = dist01*64 + m
    const int d01  = s >> 6;              // 0: BA, 1: BC
    const int m    = s & 63;
    const int tn   = tile >> 2, tk = tile & 3;

    const int gx = 1;                     // x is always B
    const int gy = d01 ? 2 : 0;           // y: A for BA, C for BC

    const char* Xa = (const char*)(Xb + (((size_t)(gx * 64 + m)) * 512 + tn * 128) * D);
    const char* Xc = (const char*)(Xb + (((size_t)(gy * 64 + m)) * 512 + tk * 128) * D);
    const float* ssx = sumsq + ((size_t)(gx * 64 + m)) * 512 + tn * 128;
    const float* ssy = sumsq + ((size_t)(gy * 64 + m)) * 512 + tk * 128;

    __shared__ unsigned short As[128 * 64];   // 16 KB, half-K A
    __shared__ unsigned short Bs[128 * 64];   // 16 KB, half-K B
    __shared__ float ss_s[256];               // x2 rows | y2 rows

    const int t = threadIdx.x;
    const int wave = t >> 6, lane = t & 63;
    const int wr = (wave >> 1) * 64;      // wave's 64x64 quadrant
    const int wc = (wave & 1) * 64;
    const int l15 = lane & 15, quad = lane >> 4;

    const int dr8 = lane >> 3, g8 = lane & 7;
    const int voff = dr8 * 256 + ((g8 ^ dr8) * 16);

    f32x4 acc[4][4] = {};

    // ---- phase 0: stage K-cols [0,64) + ss rows ----
    #pragma unroll
    for (int i = 0; i < 4; i++) {
        const int r0 = wave * 32 + i * 8;
        gl2lds16(Xa + r0 * 256 + voff, &As[r0 * 64]);
        gl2lds16(Xc + r0 * 256 + voff, &Bs[r0 * 64]);
    }
    {
        const float* sp = (wave & 2) ? ssy : ssx;
        gl2lds4(sp + (wave & 1) * 64 + lane, &ss_s[wave * 64]);
    }
    __syncthreads();

    #pragma unroll
    for (int ks = 0; ks < 2; ks++) {
        const int base = ((ks * 4 + quad) ^ (l15 & 7)) * 8;
        bf16x8 a[4], b[4];
        #pragma unroll
        for (int fr = 0; fr < 4; fr++)
            a[fr] = *(bf16x8*)&As[(wr + fr * 16 + l15) * 64 + base];
        #pragma unroll
        for (int fc = 0; fc < 4; fc++)
            b[fc] = *(bf16x8*)&Bs[(wc + fc * 16 + l15) * 64 + base];
        #pragma unroll
        for (int fr = 0; fr < 4; fr++)
            #pragma unroll
            for (int fc = 0; fc < 4; fc++)
                acc[fr][fc] = __builtin_amdgcn_mfma_f32_16x16x32_bf16(
                    a[fr], b[fc], acc[fr][fc], 0, 0, 0);
    }
    __syncthreads();

    // ---- phase 1: stage K-cols [64,128) into the same buffer ----
    #pragma unroll
    for (int i = 0; i < 4; i++) {
        const int r0 = wave * 32 + i * 8;
        gl2lds16(Xa + r0 * 256 + 128 + voff, &As[r0 * 64]);
        gl2lds16(Xc + r0 * 256 + 128 + voff, &Bs[r0 * 64]);
    }
    __syncthreads();

    #pragma unroll
    for (int ks = 0; ks < 2; ks++) {
        const int base = ((ks * 4 + quad) ^ (l15 & 7)) * 8;
        bf16x8 a[4], b[4];
        #pragma unroll
        for (int fr = 0; fr < 4; fr++)
            a[fr] = *(bf16x8*)&As[(wr + fr * 16 + l15) * 64 + base];
        #pragma unroll
        for (int fc = 0; fc < 4; fc++)
            b[fc] = *(bf16x8*)&Bs[(wc + fc * 16 + l15) * 64 + base];
        #pragma unroll
        for (int fr = 0; fr < 4; fr++)
            #pragma unroll
            for (int fc = 0; fc < 4; fc++)
                acc[fr][fc] = __builtin_amdgcn_mfma_f32_16x16x32_bf16(
                    a[fr], b[fc], acc[fr][fc], 0, 0, 0);
    }

    // ---- epilogue: d2 = x2 + y2 - 2*dot; relu(2 - d)^2 only ----
    float lsum = 0.f;
    #pragma unroll
    for (int fc = 0; fc < 4; fc++) {
        float y2 = ss_s[128 + wc + fc * 16 + l15];
        #pragma unroll
        for (int fr = 0; fr < 4; fr++) {
            #pragma unroll
            for (int i = 0; i < 4; i++) {
                float x2 = ss_s[wr + fr * 16 + quad * 4 + i];
                float d2 = fmaxf(fmaf(-2.f, acc[fr][fc][i], x2 + y2), 1e-12f);
                if (d2 < 4.f) {                       // relu(M - d), M=2
                    float td = 2.f - sqrtf(d2);
                    lsum += td * td;
                }
            }
        }
    }

    #pragma unroll
    for (int o = 32; o > 0; o >>= 1) lsum += __shfl_down(lsum, o, 64);
    __syncthreads();                      // ss_s reads done; safe to reuse
    float* red = ss_s;
    if (lane == 0) red[wave] = lsum;
    __syncthreads();
    if (t == 0)
        pslots[bx] = red[0] + red[1] + red[2] + red[3];   // plain store, no atomic
}

// Final reduction: neg from pslots; pos analytically:
// pos = (sum sumsq_A + sum sumsq_C)/(64*512) - 2*sum_mc(S_A . S_C)/(64*512^2)
// Column sums assembled from the 4 row-chunk partials in Psum.
__global__ __launch_bounds__(256) void reduce_kernel(
    const float* __restrict__ pslots, const float* __restrict__ sumsq,
    const float* __restrict__ Psum, float* __restrict__ out)
{
    const int t = threadIdx.x;
    float neg = 0.f;
    #pragma unroll
    for (int i = 0; i < 2; i++) {
        float4 v = ((const float4*)pslots)[t + i * 256];
        neg += v.x + v.y + v.z + v.w;
    }
    float ssum = 0.f;
    for (int i = t; i < 8192; i += 256) {          // 32768 floats each, as float4
        float4 v = ((const float4*)sumsq)[i];               // group A rows
        float4 w = ((const float4*)(sumsq + 65536))[i];     // group C rows
        ssum += v.x + v.y + v.z + v.w + w.x + w.y + w.z + w.w;
    }
    float dot = 0.f;
    for (int i = t; i < 2048; i += 256) {          // 64 mc x 32 float4 dims
        int mc = i >> 5, d4 = i & 31;
        float4 a = make_float4(0.f, 0.f, 0.f, 0.f);
        float4 c = make_float4(0.f, 0.f, 0.f, 0.f);
        #pragma unroll
        for (int ch = 0; ch < 4; ch++) {
            float4 av = ((const float4*)(Psum + ((size_t)(mc * 4 + ch)) * 128))[d4];
            float4 cv = ((const float4*)(Psum + ((size_t)((64 + mc) * 4 + ch)) * 128))[d4];
            a.x += av.x; a.y += av.y; a.z += av.z; a.w += av.w;
            c.x += cv.x; c.y += cv.y; c.z += cv.z; c.w += cv.w;
        }
        dot += a.x * c.x + a.y * c.y + a.z * c.z + a.w * c.w;
    }
    #pragma unroll
    for (int o = 32; o > 0; o >>= 1) {
        neg  += __shfl_down(neg,  o, 64);
        ssum += __shfl_down(ssum, o, 64);
        dot  += __shfl_down(dot,  o, 64);
    }
    __shared__ float r0[4], r1[4], r2[4];
    const int wave = t >> 6, lane = t & 63;
    if (lane == 0) { r0[wave] = neg; r1[wave] = ssum; r2[wave] = dot; }
    __syncthreads();
    if (t == 0) {
        float neg_t  = r0[0] + r0[1] + r0[2] + r0[3];
        float ssum_t = r1[0] + r1[1] + r1[2] + r1[3];
        float dot_t  = r2[0] + r2[1] + r2[2] + r2[3];
        float pos = ssum_t * (1.f / 32768.f) - 2.f * dot_t * (1.f / 16777216.f);
        out[0] = pos + neg_t * INV_COUNT;
    }
}

extern "C" void kernel_launch(void* const* d_in, const int* in_sizes, int n_in,
                              void* d_out, int out_size, void* d_ws, size_t ws_size,
                              hipStream_t stream) {
    const float* mu    = (const float*)d_in[0];
    const float* sigma = (const float*)d_in[1];
    const float* epsA  = (const float*)d_in[2];
    const float* epsB  = (const float*)d_in[3];
    const float* epsC  = (const float*)d_in[4];
    float* out = (float*)d_out;

    unsigned short* Xb = (unsigned short*)d_ws;              // 25.17 MB bf16
    float* sumsq  = (float*)((char*)d_ws + X_ELEMS * sizeof(unsigned short)); // 384 KB
    float* pslots = sumsq + NROW;                            // 8 KB partials
    float* Psum   = pslots + NBLK;                           // 256 KB chunk col sums

    prep_kernel<<<NROW / 8, 256, 0, stream>>>(mu, sigma, epsA, epsB, epsC, Xb, sumsq);

    colsum_kernel<<<512, 256, 0, stream>>>(Xb, Psum);

    dist_kernel<<<NBLK, 256, 0, stream>>>(Xb, sumsq, pslots);

    reduce_kernel<<<1, 256, 0, stream>>>(pslots, sumsq, Psum, out);
}